// Round 1
// baseline (13915.529 us; speedup 1.0000x reference)
//
#include <hip/hip_runtime.h>
#include <stdint.h>

#define SLEN 4096
#define EDIM 256
#define HD 256
#define G4 1024   // 4*HD
#define KT 20
#define START_ID 18
#define STOP_ID 19

typedef _Float16 half_t;
typedef _Float16 half2_t __attribute__((ext_vector_type(2)));

__device__ __forceinline__ float dot2(uint32_t w, uint32_t h, float acc) {
#if __has_builtin(__builtin_amdgcn_fdot2)
    return __builtin_amdgcn_fdot2(__builtin_bit_cast(half2_t, w),
                                  __builtin_bit_cast(half2_t, h), acc, false);
#else
    half2_t wv = __builtin_bit_cast(half2_t, w);
    half2_t hv = __builtin_bit_cast(half2_t, h);
    acc += (float)wv.x * (float)hv.x;
    acc += (float)wv.y * (float)hv.y;
    return acc;
#endif
}

__device__ __forceinline__ float fsig(float x) { return 1.f / (1.f + __expf(-x)); }
__device__ __forceinline__ float ftanh(float x) { return 1.f - 2.f / (__expf(2.f * x) + 1.f); }

// thread-id -> gate row mapping shared by pack/zx/lstm kernels:
//   w = t>>6, l = t&63, j = 16*w + (l&15), g = (l>>4)&3, row o = g*256 + j

// ---------------- prep: transpose w_ih into [d][e][o] ----------------
__global__ __launch_bounds__(256) void k_transpose_ih(const float* __restrict__ wf,
                                                      const float* __restrict__ wb,
                                                      float* __restrict__ wT) {
    __shared__ float tile[32][33];
    int d = blockIdx.z;
    const float* w = d ? wb : wf;
    int ob = blockIdx.x * 32;  // over 1024 rows
    int eb = blockIdx.y * 32;  // over 256 cols
    int tx = threadIdx.x & 31, ty = threadIdx.x >> 5;
#pragma unroll
    for (int r = 0; r < 32; r += 8)
        tile[ty + r][tx] = w[(long)(ob + ty + r) * EDIM + eb + tx];
    __syncthreads();
    float* dst = wT + (long)d * EDIM * G4;
#pragma unroll
    for (int r = 0; r < 32; r += 8)
        dst[(long)(eb + ty + r) * G4 + ob + tx] = tile[tx][ty + r];
}

// ---------------- prep: pack w_hh to fp16 in lstm thread order ----------------
__global__ __launch_bounds__(1024) void k_pack_hh(const float* __restrict__ whf,
                                                  const float* __restrict__ whb,
                                                  uint32_t* __restrict__ wpack,
                                                  uint32_t* __restrict__ wtail) {
    int d = blockIdx.y;
    const float* W = d ? whb : whf;
    int t = threadIdx.x;
    int wv = t >> 6, l = t & 63;
    int j = (wv << 4) | (l & 15);
    int g = (l >> 4) & 3;
    int o = g * 256 + j;
    int bx = blockIdx.x;  // 0..95 -> wpack columns, 96..103 -> wtail groups
    if (bx < 96) {
        int k = bx * 2;
        half2_t p = {(half_t)W[(long)o * HD + k], (half_t)W[(long)o * HD + k + 1]};
        wpack[(d * 96 + bx) * 1024 + t] = __builtin_bit_cast(uint32_t, p);
    } else {
        int kb = bx - 96;
        uint32_t q[4];
#pragma unroll
        for (int qq = 0; qq < 4; qq++) {
            int k = 192 + kb * 8 + qq * 2;
            half2_t p = {(half_t)W[(long)o * HD + k], (half_t)W[(long)o * HD + k + 1]};
            q[qq] = __builtin_bit_cast(uint32_t, p);
        }
        uint4* dst = (uint4*)wtail;
        dst[(d * 8 + kb) * 1024 + t] = make_uint4(q[0], q[1], q[2], q[3]);
    }
}

// ---------------- input projections: zxp[d][s][t] = (x_s @ w_ih^T + b)[o(t)] ----------------
__global__ __launch_bounds__(256) void k_zx(const int* __restrict__ sentence,
                                            const float* __restrict__ embed,
                                            const float* __restrict__ wT,
                                            const float* __restrict__ bf,
                                            const float* __restrict__ bb,
                                            float* __restrict__ zxp) {
    int d = blockIdx.y;
    int s0 = blockIdx.x * 16;
    const float* bias = d ? bb : bf;
    __shared__ float xbuf[16][EDIM];
    int tid = threadIdx.x;
    for (int r = 0; r < 16; r++) {
        int row = sentence[s0 + r];
        xbuf[r][tid] = embed[(long)row * EDIM + tid];
    }
    __syncthreads();
    const float* wTd = wT + (long)d * EDIM * G4;
    for (int og = 0; og < 4; og++) {
        float acc[16];
#pragma unroll
        for (int r = 0; r < 16; r++) acc[r] = 0.f;
        int o = og * 256 + tid;
        for (int e = 0; e < EDIM; e += 4) {
            float w0 = wTd[(long)(e + 0) * G4 + o];
            float w1 = wTd[(long)(e + 1) * G4 + o];
            float w2 = wTd[(long)(e + 2) * G4 + o];
            float w3 = wTd[(long)(e + 3) * G4 + o];
#pragma unroll
            for (int r = 0; r < 16; r++) {
                float4 x4 = *(const float4*)&xbuf[r][e];
                acc[r] += w0 * x4.x + w1 * x4.y + w2 * x4.z + w3 * x4.w;
            }
        }
        float bv = bias[o];
        int tB = ((tid >> 4) << 6) | (og << 4) | (tid & 15);
#pragma unroll
        for (int r = 0; r < 16; r++)
            zxp[(long)(d * SLEN + s0 + r) * G4 + tB] = acc[r] + bv;
    }
}

// ---------------- the serial BiLSTM: 2 blocks (one per direction) ----------------
__global__ __launch_bounds__(1024) void k_lstm(const float* __restrict__ zxp,
                                               const uint32_t* __restrict__ wpack,
                                               const uint4* __restrict__ wtail,
                                               const float* __restrict__ h0,
                                               const float* __restrict__ c0,
                                               float* __restrict__ hs) {
    int d = blockIdx.x;
    int t = threadIdx.x;
    int l = t & 63;
    int j = ((t >> 6) << 4) | (l & 15);

    uint32_t wreg[96];
#pragma unroll
    for (int kk = 0; kk < 96; kk++) wreg[kk] = wpack[(d * 96 + kk) * 1024 + t];

    __shared__ uint4 h2q[2][32];            // [buf][32 uint4] = 256 fp16 h values
    half_t* h2h = (half_t*)h2q;             // [buf*256 + j]

    float c = c0[d * HD + j];
    if (t < 128) {
        half2_t p = {(half_t)h0[d * HD + 2 * t], (half_t)h0[d * HD + 2 * t + 1]};
        ((uint32_t*)h2q)[t] = __builtin_bit_cast(uint32_t, p);
    }
    __syncthreads();

    const uint4* wt = wtail + (long)d * 8 * 1024 + t;
    const float* zxd = zxp + (long)d * SLEN * G4 + t;
    float* hsd = hs + (long)d * SLEN * HD + j;

    for (int s = 0; s < SLEN; s++) {
        const int p = s & 1;
        const int sx = d ? (SLEN - 1 - s) : s;
        float zx = zxd[(long)sx * G4];
        const uint4* hq = h2q[p];
        float acc0 = 0.f, acc1 = 0.f;
        uint4 tw[4];
#pragma unroll
        for (int kb = 0; kb < 4; kb++) tw[kb] = wt[kb * 1024];
#pragma unroll
        for (int kk4 = 0; kk4 < 12; kk4++) {
            uint4 hv = hq[kk4];
            acc0 = dot2(wreg[4 * kk4 + 0], hv.x, acc0);
            acc1 = dot2(wreg[4 * kk4 + 1], hv.y, acc1);
            acc0 = dot2(wreg[4 * kk4 + 2], hv.z, acc0);
            acc1 = dot2(wreg[4 * kk4 + 3], hv.w, acc1);
        }
#pragma unroll
        for (int kb = 0; kb < 4; kb++) {
            uint4 hv = hq[24 + kb];
            acc0 = dot2(tw[kb].x, hv.x, acc0);
            acc1 = dot2(tw[kb].y, hv.y, acc1);
            acc0 = dot2(tw[kb].z, hv.z, acc0);
            acc1 = dot2(tw[kb].w, hv.w, acc1);
        }
#pragma unroll
        for (int kb = 0; kb < 4; kb++) tw[kb] = wt[(4 + kb) * 1024];
#pragma unroll
        for (int kk4 = 12; kk4 < 24; kk4++) {
            uint4 hv = hq[kk4];
            acc0 = dot2(wreg[4 * kk4 + 0], hv.x, acc0);
            acc1 = dot2(wreg[4 * kk4 + 1], hv.y, acc1);
            acc0 = dot2(wreg[4 * kk4 + 2], hv.z, acc0);
            acc1 = dot2(wreg[4 * kk4 + 3], hv.w, acc1);
        }
#pragma unroll
        for (int kb = 0; kb < 4; kb++) {
            uint4 hv = hq[28 + kb];
            acc0 = dot2(tw[kb].x, hv.x, acc0);
            acc1 = dot2(tw[kb].y, hv.y, acc1);
            acc0 = dot2(tw[kb].z, hv.z, acc0);
            acc1 = dot2(tw[kb].w, hv.w, acc1);
        }
        float z = acc0 + acc1 + zx;
        int lj = l & 15;
        float zi = __shfl(z, lj, 64);
        float zf = __shfl(z, lj + 16, 64);
        float zg = __shfl(z, lj + 32, 64);
        float zo = __shfl(z, lj + 48, 64);
        float ig = fsig(zi), fg = fsig(zf), og = fsig(zo);
        float gg = ftanh(zg);
        c = fg * c + ig * gg;
        float hval = og * ftanh(c);
        if (l < 16) {
            hsd[(long)sx * HD] = hval;
            h2h[((p ^ 1) << 8) + j] = (half_t)hval;
        }
        __syncthreads();
    }
}

// ---------------- feats[s][k] = emitW[k] . [h_fwd[s], h_bwd[s]] + emit_b[k] ----------------
__global__ __launch_bounds__(192) void k_feats(const float* __restrict__ hs,
                                               const float* __restrict__ emitW,
                                               const float* __restrict__ emitb,
                                               float* __restrict__ feats) {
    __shared__ float wb[KT][516];
    __shared__ float hb[8][516];
    int tid = threadIdx.x;
    int s0 = blockIdx.x * 8;
    for (int idx = tid; idx < KT * 512; idx += 192) {
        wb[idx >> 9][idx & 511] = emitW[idx];
    }
    for (int idx = tid; idx < 8 * 512; idx += 192) {
        int sl = idx >> 9, jj = idx & 511;
        float v = (jj < 256) ? hs[(long)(s0 + sl) * HD + jj]
                             : hs[(long)(SLEN + s0 + sl) * HD + (jj - 256)];
        hb[sl][jj] = v;
    }
    __syncthreads();
    if (tid < 160) {
        int sl = tid / KT, k = tid % KT;
        float acc = emitb[k];
        for (int jj = 0; jj < 512; jj += 4) {
            float4 wv = *(const float4*)&wb[k][jj];
            float4 hv = *(const float4*)&hb[sl][jj];
            acc += wv.x * hv.x + wv.y * hv.y + wv.z * hv.z + wv.w * hv.w;
        }
        feats[(long)(s0 + sl) * KT + k] = acc;
    }
}

// ---------------- gold path score -> out[1] ----------------
__global__ __launch_bounds__(256) void k_gold(const float* __restrict__ feats,
                                              const int* __restrict__ tags,
                                              const float* __restrict__ trans,
                                              float* __restrict__ out) {
    __shared__ float red[256];
    int tid = threadIdx.x;
    float local = 0.f;
    for (int s2 = tid; s2 < SLEN; s2 += 256) {
        int cur = tags[s2];
        int prev = s2 ? tags[s2 - 1] : START_ID;
        local += trans[cur * KT + prev] + feats[(long)s2 * KT + cur];
    }
    red[tid] = local;
    __syncthreads();
    for (int off = 128; off; off >>= 1) {
        if (tid < off) red[tid] += red[tid + off];
        __syncthreads();
    }
    if (tid == 0) out[1] = red[0] + trans[STOP_ID * KT + tags[SLEN - 1]];
}

// ---------------- CRF: chunk of 16 step-matrices -> one 20x20 log-space matrix ----------------
__global__ __launch_bounds__(512) void k_crf_chunk(const float* __restrict__ feats,
                                                   const float* __restrict__ trans,
                                                   float* __restrict__ mats) {
    __shared__ float T[KT][KT + 1];
    __shared__ float fb[16][KT];
    __shared__ float cur[2][KT][KT + 1];
    int tid = threadIdx.x;
    int t0 = blockIdx.x * 16;
    if (tid < KT * KT) T[tid / KT][tid % KT] = trans[tid];
    for (int idx = tid; idx < 16 * KT; idx += 512) fb[idx / KT][idx % KT] = feats[(long)t0 * KT + idx];
    __syncthreads();
    int i = tid / KT, jc = tid % KT;
    bool act = tid < KT * KT;
    if (act) cur[0][i][jc] = T[i][jc] + fb[0][i];
    __syncthreads();
    for (int m = 1; m < 16; m++) {
        int p = (m - 1) & 1;
        float nv = 0.f;
        if (act) {
            float vs[KT], vmax = -1e30f;
#pragma unroll
            for (int k = 0; k < KT; k++) { vs[k] = T[i][k] + cur[p][k][jc]; vmax = fmaxf(vmax, vs[k]); }
            float sum = 0.f;
#pragma unroll
            for (int k = 0; k < KT; k++) sum += __expf(vs[k] - vmax);
            nv = fb[m][i] + vmax + __logf(sum);
        }
        if (act) cur[p ^ 1][i][jc] = nv;
        __syncthreads();
    }
    if (act) mats[(long)blockIdx.x * (KT * KT) + tid] = cur[1][i][jc];
}

// ---------------- CRF: combine per_block consecutive matrices (left-applied) ----------------
__global__ __launch_bounds__(512) void k_crf_combine(const float* __restrict__ in,
                                                     float* __restrict__ out_mats,
                                                     int per_block,
                                                     const float* __restrict__ trans,
                                                     float* __restrict__ d_out_ptr,
                                                     int finalize) {
    __shared__ float A[KT][KT + 1];
    __shared__ float cur[2][KT][KT + 1];
    int tid = threadIdx.x;
    int b = blockIdx.x;
    int i = tid / KT, jc = tid % KT;
    bool act = tid < KT * KT;
    const float* base = in + (long)b * per_block * (KT * KT);
    if (act) cur[0][i][jc] = base[tid];
    __syncthreads();
    for (int m = 1; m < per_block; m++) {
        int p = (m - 1) & 1;
        if (act) A[i][jc] = base[(long)m * KT * KT + tid];
        __syncthreads();
        float nv = 0.f;
        if (act) {
            float vs[KT], vmax = -1e30f;
#pragma unroll
            for (int k = 0; k < KT; k++) { vs[k] = A[i][k] + cur[p][k][jc]; vmax = fmaxf(vmax, vs[k]); }
            float sum = 0.f;
#pragma unroll
            for (int k = 0; k < KT; k++) sum += __expf(vs[k] - vmax);
            nv = vmax + __logf(sum);
        }
        if (act) cur[p ^ 1][i][jc] = nv;
        __syncthreads();
    }
    int fbuf = (per_block - 1) & 1;
    if (!finalize) {
        if (act) out_mats[(long)b * KT * KT + tid] = cur[fbuf][i][jc];
        return;
    }
    if (tid == 0) {
        float fv[KT];
        for (int ii = 0; ii < KT; ii++) {
            float vs[KT], vmax = -1e30f;
            for (int k = 0; k < KT; k++) {
                float v = cur[fbuf][ii][k] + (k == START_ID ? 0.f : -10000.f);
                vs[k] = v;
                vmax = fmaxf(vmax, v);
            }
            float sum = 0.f;
            for (int k = 0; k < KT; k++) sum += __expf(vs[k] - vmax);
            fv[ii] = vmax + __logf(sum);
        }
        float vs2[KT], vmax = -1e30f;
        for (int ii = 0; ii < KT; ii++) {
            float v = fv[ii] + trans[STOP_ID * KT + ii];
            vs2[ii] = v;
            vmax = fmaxf(vmax, v);
        }
        float sum = 0.f;
        for (int ii = 0; ii < KT; ii++) sum += __expf(vs2[ii] - vmax);
        d_out_ptr[0] = vmax + __logf(sum);
    }
}

extern "C" void kernel_launch(void* const* d_in, const int* in_sizes, int n_in,
                              void* d_out, int out_size, void* d_ws, size_t ws_size,
                              hipStream_t stream) {
    const int* sentence = (const int*)d_in[0];
    const int* tags = (const int*)d_in[1];
    const float* embed = (const float*)d_in[2];
    const float* w_ih_f = (const float*)d_in[3];
    const float* w_hh_f = (const float*)d_in[4];
    const float* b_f = (const float*)d_in[5];
    const float* w_ih_b = (const float*)d_in[6];
    const float* w_hh_b = (const float*)d_in[7];
    const float* b_b = (const float*)d_in[8];
    const float* h0 = (const float*)d_in[9];
    const float* c0 = (const float*)d_in[10];
    const float* emit_W = (const float*)d_in[11];
    const float* emit_b = (const float*)d_in[12];
    const float* transition = (const float*)d_in[13];
    float* out = (float*)d_out;

    char* ws = (char*)d_ws;
    float* zxp = (float*)(ws + 0);                       // 2*4096*1024 f32 = 32 MB
    float* hs = (float*)(ws + 33554432);                 // 2*4096*256 f32  = 8 MB
    float* wT = (float*)(ws + 41943040);                 // 2*256*1024 f32  = 2 MB
    uint32_t* wpack = (uint32_t*)(ws + 44040192);        // 2*96*1024 u32
    uint32_t* wtail = (uint32_t*)(ws + 44826624);        // 2*8*1024*4 u32
    float* feats = (float*)(ws + 45088768);              // 4096*20 f32
    float* mats = (float*)(ws + 45416448);               // 256*400 f32
    float* mats2 = (float*)(ws + 45826048);              // 16*400 f32

    k_transpose_ih<<<dim3(32, 8, 2), 256, 0, stream>>>(w_ih_f, w_ih_b, wT);
    k_pack_hh<<<dim3(104, 2), 1024, 0, stream>>>(w_hh_f, w_hh_b, wpack, wtail);
    k_zx<<<dim3(256, 2), 256, 0, stream>>>(sentence, embed, wT, b_f, b_b, zxp);
    k_lstm<<<dim3(2), 1024, 0, stream>>>(zxp, wpack, (const uint4*)wtail, h0, c0, hs);
    k_feats<<<dim3(512), 192, 0, stream>>>(hs, emit_W, emit_b, feats);
    k_gold<<<dim3(1), 256, 0, stream>>>(feats, tags, transition, out);
    k_crf_chunk<<<dim3(256), 512, 0, stream>>>(feats, transition, mats);
    k_crf_combine<<<dim3(16), 512, 0, stream>>>(mats, mats2, 16, transition, out, 0);
    k_crf_combine<<<dim3(1), 512, 0, stream>>>(mats2, nullptr, 16, transition, out, 1);
}

// Round 2
// 9015.471 us; speedup vs baseline: 1.5435x; 1.5435x over previous
//
#include <hip/hip_runtime.h>
#include <stdint.h>

#define SLEN 4096
#define EDIM 256
#define HD 256
#define G4 1024   // 4*HD
#define KT 20
#define START_ID 18
#define STOP_ID 19

// weight split for k_lstm: 32 K-chunks of 4 dwords (8 fp16) each.
// chunks 0..22 (92 dwords) live in VGPRs; chunks 23..31 (36 dwords) live in LDS.
#define NVC 23          // VGPR chunks
#define NLC 9           // LDS chunks
#define LSTM_LDS_BYTES (1024 + 1024 * NLC * 16)   // h dbuf (2*512B) + tail weights

typedef _Float16 half_t;
typedef _Float16 half2_t __attribute__((ext_vector_type(2)));

__device__ __forceinline__ float dot2(uint32_t w, uint32_t h, float acc) {
#if __has_builtin(__builtin_amdgcn_fdot2)
    return __builtin_amdgcn_fdot2(__builtin_bit_cast(half2_t, w),
                                  __builtin_bit_cast(half2_t, h), acc, false);
#else
    half2_t wv = __builtin_bit_cast(half2_t, w);
    half2_t hv = __builtin_bit_cast(half2_t, h);
    acc += (float)wv.x * (float)hv.x;
    acc += (float)wv.y * (float)hv.y;
    return acc;
#endif
}

__device__ __forceinline__ float fsig(float x) { return 1.f / (1.f + __expf(-x)); }
__device__ __forceinline__ float ftanh(float x) { return 1.f - 2.f / (__expf(2.f * x) + 1.f); }

// thread-id -> gate row mapping shared by pack/zx/lstm kernels:
//   w = t>>6, l = t&63, j = 16*w + (l&15), g = (l>>4)&3, row o = g*256 + j

// ---------------- prep: transpose w_ih into [d][e][o] ----------------
__global__ __launch_bounds__(256) void k_transpose_ih(const float* __restrict__ wf,
                                                      const float* __restrict__ wb,
                                                      float* __restrict__ wT) {
    __shared__ float tile[32][33];
    int d = blockIdx.z;
    const float* w = d ? wb : wf;
    int ob = blockIdx.x * 32;  // over 1024 rows
    int eb = blockIdx.y * 32;  // over 256 cols
    int tx = threadIdx.x & 31, ty = threadIdx.x >> 5;
#pragma unroll
    for (int r = 0; r < 32; r += 8)
        tile[ty + r][tx] = w[(long)(ob + ty + r) * EDIM + eb + tx];
    __syncthreads();
    float* dst = wT + (long)d * EDIM * G4;
#pragma unroll
    for (int r = 0; r < 32; r += 8)
        dst[(long)(eb + ty + r) * G4 + ob + tx] = tile[tx][ty + r];
}

// ---------------- prep: pack w_hh to fp16 in lstm thread order ----------------
__global__ __launch_bounds__(1024) void k_pack_hh(const float* __restrict__ whf,
                                                  const float* __restrict__ whb,
                                                  uint32_t* __restrict__ wpack,
                                                  uint32_t* __restrict__ wtail) {
    int d = blockIdx.y;
    const float* W = d ? whb : whf;
    int t = threadIdx.x;
    int wv = t >> 6, l = t & 63;
    int j = (wv << 4) | (l & 15);
    int g = (l >> 4) & 3;
    int o = g * 256 + j;
    int bx = blockIdx.x;  // 0..91 -> wpack dwords, 92..100 -> wtail chunks
    if (bx < 92) {
        int k = bx * 2;
        half2_t p = {(half_t)W[(long)o * HD + k], (half_t)W[(long)o * HD + k + 1]};
        wpack[(d * 92 + bx) * 1024 + t] = __builtin_bit_cast(uint32_t, p);
    } else {
        int cb = bx - 92;
        uint32_t q[4];
#pragma unroll
        for (int qq = 0; qq < 4; qq++) {
            int k = 2 * (92 + cb * 4 + qq);
            half2_t p = {(half_t)W[(long)o * HD + k], (half_t)W[(long)o * HD + k + 1]};
            q[qq] = __builtin_bit_cast(uint32_t, p);
        }
        uint4* dst = (uint4*)wtail;
        dst[(d * NLC + cb) * 1024 + t] = make_uint4(q[0], q[1], q[2], q[3]);
    }
}

// ---------------- input projections: zxp[d][s][t] = (x_s @ w_ih^T + b)[o(t)] ----------------
__global__ __launch_bounds__(256) void k_zx(const int* __restrict__ sentence,
                                            const float* __restrict__ embed,
                                            const float* __restrict__ wT,
                                            const float* __restrict__ bf,
                                            const float* __restrict__ bb,
                                            float* __restrict__ zxp) {
    int d = blockIdx.y;
    int s0 = blockIdx.x * 16;
    const float* bias = d ? bb : bf;
    __shared__ float xbuf[16][EDIM];
    int tid = threadIdx.x;
    for (int r = 0; r < 16; r++) {
        int row = sentence[s0 + r];
        xbuf[r][tid] = embed[(long)row * EDIM + tid];
    }
    __syncthreads();
    const float* wTd = wT + (long)d * EDIM * G4;
    for (int og = 0; og < 4; og++) {
        float acc[16];
#pragma unroll
        for (int r = 0; r < 16; r++) acc[r] = 0.f;
        int o = og * 256 + tid;
        for (int e = 0; e < EDIM; e += 4) {
            float w0 = wTd[(long)(e + 0) * G4 + o];
            float w1 = wTd[(long)(e + 1) * G4 + o];
            float w2 = wTd[(long)(e + 2) * G4 + o];
            float w3 = wTd[(long)(e + 3) * G4 + o];
#pragma unroll
            for (int r = 0; r < 16; r++) {
                float4 x4 = *(const float4*)&xbuf[r][e];
                acc[r] += w0 * x4.x + w1 * x4.y + w2 * x4.z + w3 * x4.w;
            }
        }
        float bv = bias[o];
        int tB = ((tid >> 4) << 6) | (og << 4) | (tid & 15);
#pragma unroll
        for (int r = 0; r < 16; r++)
            zxp[(long)(d * SLEN + s0 + r) * G4 + tB] = acc[r] + bv;
    }
}

// ---------------- the serial BiLSTM: 2 blocks (one per direction) ----------------
// __launch_bounds__(1024,4): 4 waves/EU min -> 1 block/CU -> 128-VGPR cap (not 64).
// 92 weight dwords in VGPR, 36 in dynamic LDS (147KB, opt-in past 64KB).
__global__ __launch_bounds__(1024, 4) void k_lstm(const float* __restrict__ zxp,
                                                  const uint32_t* __restrict__ wpack,
                                                  const uint4* __restrict__ wtail,
                                                  const float* __restrict__ h0,
                                                  const float* __restrict__ c0,
                                                  float* __restrict__ hs) {
    extern __shared__ char smem[];
    uint4* h2q = (uint4*)smem;              // [2][32] uint4 = 2 x 256 fp16 h
    half_t* h2h = (half_t*)smem;            // [buf*256 + j]
    uint4* tail = (uint4*)(smem + 1024);    // [NLC][1024] per-thread tail weights

    int d = blockIdx.x;
    int t = threadIdx.x;
    int l = t & 63;
    int j = ((t >> 6) << 4) | (l & 15);

    uint32_t wreg[4 * NVC];
#pragma unroll
    for (int kk = 0; kk < 4 * NVC; kk++) wreg[kk] = wpack[(d * 92 + kk) * 1024 + t];

    // stage tail weights into LDS (per-thread, lane-consecutive 16B -> conflict-free)
#pragma unroll
    for (int cb = 0; cb < NLC; cb++)
        tail[cb * 1024 + t] = wtail[(d * NLC + cb) * 1024 + t];

    float c = c0[d * HD + j];
    if (t < 128) {
        half2_t p = {(half_t)h0[d * HD + 2 * t], (half_t)h0[d * HD + 2 * t + 1]};
        ((uint32_t*)h2q)[t] = __builtin_bit_cast(uint32_t, p);
    }
    __syncthreads();

    const float* zxd = zxp + (long)d * SLEN * G4 + t;
    float* hsd = hs + (long)d * SLEN * HD + j;

    // software-pipelined zx read (hides LLC latency)
    float zx_next = zxd[(long)(d ? SLEN - 1 : 0) * G4];

    for (int s = 0; s < SLEN; s++) {
        const int p = s & 1;
        float zx = zx_next;
        if (s + 1 < SLEN) {
            int sxn = d ? (SLEN - 2 - s) : (s + 1);
            zx_next = zxd[(long)sxn * G4];
        }
        const uint4* hq = h2q + p * 32;
        float acc0 = 0.f, acc1 = 0.f;
#pragma unroll
        for (int cc = 0; cc < NVC; cc++) {
            uint4 hv = hq[cc];
            acc0 = dot2(wreg[4 * cc + 0], hv.x, acc0);
            acc1 = dot2(wreg[4 * cc + 1], hv.y, acc1);
            acc0 = dot2(wreg[4 * cc + 2], hv.z, acc0);
            acc1 = dot2(wreg[4 * cc + 3], hv.w, acc1);
        }
#pragma unroll
        for (int cb = 0; cb < NLC; cb++) {
            uint4 tw = tail[cb * 1024 + t];
            uint4 hv = hq[NVC + cb];
            acc0 = dot2(tw.x, hv.x, acc0);
            acc1 = dot2(tw.y, hv.y, acc1);
            acc0 = dot2(tw.z, hv.z, acc0);
            acc1 = dot2(tw.w, hv.w, acc1);
        }
        float z = acc0 + acc1 + zx;
        int lj = l & 15;
        float zi = __shfl(z, lj, 64);
        float zf = __shfl(z, lj + 16, 64);
        float zg = __shfl(z, lj + 32, 64);
        float zo = __shfl(z, lj + 48, 64);
        float ig = fsig(zi), fg = fsig(zf), og = fsig(zo);
        float gg = ftanh(zg);
        c = fg * c + ig * gg;
        float hval = og * ftanh(c);
        if (l < 16) {
            int sx = d ? (SLEN - 1 - s) : s;
            hsd[(long)sx * HD] = hval;
            h2h[((p ^ 1) << 8) + j] = (half_t)hval;
        }
        __syncthreads();
    }
}

// ---------------- feats[s][k] = emitW[k] . [h_fwd[s], h_bwd[s]] + emit_b[k] ----------------
__global__ __launch_bounds__(192) void k_feats(const float* __restrict__ hs,
                                               const float* __restrict__ emitW,
                                               const float* __restrict__ emitb,
                                               float* __restrict__ feats) {
    __shared__ float wb[KT][516];
    __shared__ float hb[8][516];
    int tid = threadIdx.x;
    int s0 = blockIdx.x * 8;
    for (int idx = tid; idx < KT * 512; idx += 192) {
        wb[idx >> 9][idx & 511] = emitW[idx];
    }
    for (int idx = tid; idx < 8 * 512; idx += 192) {
        int sl = idx >> 9, jj = idx & 511;
        float v = (jj < 256) ? hs[(long)(s0 + sl) * HD + jj]
                             : hs[(long)(SLEN + s0 + sl) * HD + (jj - 256)];
        hb[sl][jj] = v;
    }
    __syncthreads();
    if (tid < 160) {
        int sl = tid / KT, k = tid % KT;
        float acc = emitb[k];
        for (int jj = 0; jj < 512; jj += 4) {
            float4 wv = *(const float4*)&wb[k][jj];
            float4 hv = *(const float4*)&hb[sl][jj];
            acc += wv.x * hv.x + wv.y * hv.y + wv.z * hv.z + wv.w * hv.w;
        }
        feats[(long)(s0 + sl) * KT + k] = acc;
    }
}

// ---------------- gold path score -> out[1] ----------------
__global__ __launch_bounds__(256) void k_gold(const float* __restrict__ feats,
                                              const int* __restrict__ tags,
                                              const float* __restrict__ trans,
                                              float* __restrict__ out) {
    __shared__ float red[256];
    int tid = threadIdx.x;
    float local = 0.f;
    for (int s2 = tid; s2 < SLEN; s2 += 256) {
        int cur = tags[s2];
        int prev = s2 ? tags[s2 - 1] : START_ID;
        local += trans[cur * KT + prev] + feats[(long)s2 * KT + cur];
    }
    red[tid] = local;
    __syncthreads();
    for (int off = 128; off; off >>= 1) {
        if (tid < off) red[tid] += red[tid + off];
        __syncthreads();
    }
    if (tid == 0) out[1] = red[0] + trans[STOP_ID * KT + tags[SLEN - 1]];
}

// ---------------- CRF: chunk of 16 step-matrices -> one 20x20 log-space matrix ----------------
__global__ __launch_bounds__(512) void k_crf_chunk(const float* __restrict__ feats,
                                                   const float* __restrict__ trans,
                                                   float* __restrict__ mats) {
    __shared__ float T[KT][KT + 1];
    __shared__ float fb[16][KT];
    __shared__ float cur[2][KT][KT + 1];
    int tid = threadIdx.x;
    int t0 = blockIdx.x * 16;
    if (tid < KT * KT) T[tid / KT][tid % KT] = trans[tid];
    for (int idx = tid; idx < 16 * KT; idx += 512) fb[idx / KT][idx % KT] = feats[(long)t0 * KT + idx];
    __syncthreads();
    int i = tid / KT, jc = tid % KT;
    bool act = tid < KT * KT;
    if (act) cur[0][i][jc] = T[i][jc] + fb[0][i];
    __syncthreads();
    for (int m = 1; m < 16; m++) {
        int p = (m - 1) & 1;
        float nv = 0.f;
        if (act) {
            float vs[KT], vmax = -1e30f;
#pragma unroll
            for (int k = 0; k < KT; k++) { vs[k] = T[i][k] + cur[p][k][jc]; vmax = fmaxf(vmax, vs[k]); }
            float sum = 0.f;
#pragma unroll
            for (int k = 0; k < KT; k++) sum += __expf(vs[k] - vmax);
            nv = fb[m][i] + vmax + __logf(sum);
        }
        if (act) cur[p ^ 1][i][jc] = nv;
        __syncthreads();
    }
    if (act) mats[(long)blockIdx.x * (KT * KT) + tid] = cur[1][i][jc];
}

// ---------------- CRF: combine per_block consecutive matrices (left-applied) ----------------
__global__ __launch_bounds__(512) void k_crf_combine(const float* __restrict__ in,
                                                     float* __restrict__ out_mats,
                                                     int per_block,
                                                     const float* __restrict__ trans,
                                                     float* __restrict__ d_out_ptr,
                                                     int finalize) {
    __shared__ float A[KT][KT + 1];
    __shared__ float cur[2][KT][KT + 1];
    int tid = threadIdx.x;
    int b = blockIdx.x;
    int i = tid / KT, jc = tid % KT;
    bool act = tid < KT * KT;
    const float* base = in + (long)b * per_block * (KT * KT);
    if (act) cur[0][i][jc] = base[tid];
    __syncthreads();
    for (int m = 1; m < per_block; m++) {
        int p = (m - 1) & 1;
        if (act) A[i][jc] = base[(long)m * KT * KT + tid];
        __syncthreads();
        float nv = 0.f;
        if (act) {
            float vs[KT], vmax = -1e30f;
#pragma unroll
            for (int k = 0; k < KT; k++) { vs[k] = A[i][k] + cur[p][k][jc]; vmax = fmaxf(vmax, vs[k]); }
            float sum = 0.f;
#pragma unroll
            for (int k = 0; k < KT; k++) sum += __expf(vs[k] - vmax);
            nv = vmax + __logf(sum);
        }
        if (act) cur[p ^ 1][i][jc] = nv;
        __syncthreads();
    }
    int fbuf = (per_block - 1) & 1;
    if (!finalize) {
        if (act) out_mats[(long)b * KT * KT + tid] = cur[fbuf][i][jc];
        return;
    }
    if (tid == 0) {
        float fv[KT];
        for (int ii = 0; ii < KT; ii++) {
            float vs[KT], vmax = -1e30f;
            for (int k = 0; k < KT; k++) {
                float v = cur[fbuf][ii][k] + (k == START_ID ? 0.f : -10000.f);
                vs[k] = v;
                vmax = fmaxf(vmax, v);
            }
            float sum = 0.f;
            for (int k = 0; k < KT; k++) sum += __expf(vs[k] - vmax);
            fv[ii] = vmax + __logf(sum);
        }
        float vs2[KT], vmax = -1e30f;
        for (int ii = 0; ii < KT; ii++) {
            float v = fv[ii] + trans[STOP_ID * KT + ii];
            vs2[ii] = v;
            vmax = fmaxf(vmax, v);
        }
        float sum = 0.f;
        for (int ii = 0; ii < KT; ii++) sum += __expf(vs2[ii] - vmax);
        d_out_ptr[0] = vmax + __logf(sum);
    }
}

extern "C" void kernel_launch(void* const* d_in, const int* in_sizes, int n_in,
                              void* d_out, int out_size, void* d_ws, size_t ws_size,
                              hipStream_t stream) {
    const int* sentence = (const int*)d_in[0];
    const int* tags = (const int*)d_in[1];
    const float* embed = (const float*)d_in[2];
    const float* w_ih_f = (const float*)d_in[3];
    const float* w_hh_f = (const float*)d_in[4];
    const float* b_f = (const float*)d_in[5];
    const float* w_ih_b = (const float*)d_in[6];
    const float* w_hh_b = (const float*)d_in[7];
    const float* b_b = (const float*)d_in[8];
    const float* h0 = (const float*)d_in[9];
    const float* c0 = (const float*)d_in[10];
    const float* emit_W = (const float*)d_in[11];
    const float* emit_b = (const float*)d_in[12];
    const float* transition = (const float*)d_in[13];
    float* out = (float*)d_out;

    char* ws = (char*)d_ws;
    float* zxp = (float*)(ws + 0);                       // 2*4096*1024 f32 = 32 MB
    float* hs = (float*)(ws + 33554432);                 // 2*4096*256 f32  = 8 MB
    float* wT = (float*)(ws + 41943040);                 // 2*256*1024 f32  = 2 MB
    uint32_t* wpack = (uint32_t*)(ws + 44040192);        // 2*92*1024 u32 = 736 KB
    uint32_t* wtail = (uint32_t*)(ws + 44793856);        // 2*9*1024*4 u32 = 288 KB
    float* feats = (float*)(ws + 45088768);              // 4096*20 f32
    float* mats = (float*)(ws + 45416448);               // 256*400 f32
    float* mats2 = (float*)(ws + 45826048);              // 16*400 f32

    // opt-in to >64KB dynamic LDS for k_lstm (idempotent host call, not a stream op)
    (void)hipFuncSetAttribute((const void*)k_lstm,
                              hipFuncAttributeMaxDynamicSharedMemorySize,
                              LSTM_LDS_BYTES);

    k_transpose_ih<<<dim3(32, 8, 2), 256, 0, stream>>>(w_ih_f, w_ih_b, wT);
    k_pack_hh<<<dim3(101, 2), 1024, 0, stream>>>(w_hh_f, w_hh_b, wpack, wtail);
    k_zx<<<dim3(256, 2), 256, 0, stream>>>(sentence, embed, wT, b_f, b_b, zxp);
    k_lstm<<<dim3(2), 1024, LSTM_LDS_BYTES, stream>>>(zxp, wpack, (const uint4*)wtail, h0, c0, hs);
    k_feats<<<dim3(512), 192, 0, stream>>>(hs, emit_W, emit_b, feats);
    k_gold<<<dim3(1), 256, 0, stream>>>(feats, tags, transition, out);
    k_crf_chunk<<<dim3(256), 512, 0, stream>>>(feats, transition, mats);
    k_crf_combine<<<dim3(16), 512, 0, stream>>>(mats, mats2, 16, transition, out, 0);
    k_crf_combine<<<dim3(1), 512, 0, stream>>>(mats2, nullptr, 16, transition, out, 1);
}